// Round 7
// baseline (265.962 us; speedup 1.0000x reference)
//
#include <hip/hip_runtime.h>
#include <hip/hip_bf16.h>
#include <hip/hip_fp8.h>

#define MROWS 8192   // N*T
#define KDIM  512    // CIN
#define NCOL  8192   // codebook size K
#define TSEQ  2048

typedef float f32x4 __attribute__((ext_vector_type(4)));

__device__ __forceinline__ unsigned char f2fp8(float x) {
  __hip_fp8_e4m3 h(x);
  return h.__x;
}
__device__ __forceinline__ float fp82f(unsigned char b) {
  __hip_fp8_e4m3 h; h.__x = b;
  return (float)h;
}

// ---------------- prep: context->fp8, W_enc transpose->fp8, fproj ----------------
// blocks [0,4096): convA   [4096,8192): convB-transpose   [8192,8704): fproj
__global__ void prep_kernel(const float* __restrict__ X, unsigned char* __restrict__ A8,
                            const float* __restrict__ W, unsigned char* __restrict__ B8,
                            const float* __restrict__ feats, const float* __restrict__ proj,
                            float* __restrict__ fnorm) {
  __shared__ float tile[32][33];
  const int tid = threadIdx.x;
  int b = blockIdx.x;
  if (b < 4096) {
    int i = b * 256 + tid;                 // float4 index
    float4 v = reinterpret_cast<const float4*>(X)[i];
    uchar4 o;
    o.x = f2fp8(v.x); o.y = f2fp8(v.y); o.z = f2fp8(v.z); o.w = f2fp8(v.w);
    reinterpret_cast<uchar4*>(A8)[i] = o;
  } else if (b < 8192) {
    b -= 4096;
    const int bx = b & 255, by = b >> 8;    // 256 x 16 tiles of 32x32
    const int tx = tid & 31, ty = tid >> 5; // 32 x 8
    #pragma unroll
    for (int i = 0; i < 32; i += 8)
      tile[ty + i][tx] = W[(size_t)(by * 32 + ty + i) * NCOL + bx * 32 + tx];
    __syncthreads();
    #pragma unroll
    for (int i = 0; i < 32; i += 8)
      B8[(size_t)(bx * 32 + ty + i) * KDIM + by * 32 + tx] = f2fp8(tile[tx][ty + i]);
  } else {
    b -= 8192;
    int rl = tid >> 4, d = tid & 15;
    int row = b * 16 + rl;
    const float4* fr4 = reinterpret_cast<const float4*>(feats + (size_t)row * KDIM);
    float acc = 0.f;
    #pragma unroll 4
    for (int kc = 0; kc < KDIM / 4; ++kc) {
      float4 v = fr4[kc];
      const float* p = proj + (size_t)kc * 64 + d;
      acc += v.x * p[0] + v.y * p[16] + v.z * p[32] + v.w * p[48];
    }
    float s = acc * acc;
    #pragma unroll
    for (int o = 1; o < 16; o <<= 1) s += __shfl_xor(s, o);
    float nrm = sqrtf(s);
    fnorm[(size_t)row * 16 + d] = acc / fmaxf(nrm, 1e-12f);
  }
}

// ---------------- nearest codebook: 4 rows/thread ----------------
#define CB_CODES 128
__global__ __launch_bounds__(256)
void targets_part_kernel(const float* __restrict__ fnorm, const float* __restrict__ cb,
                         float* __restrict__ pval, int* __restrict__ pidx) {
  __shared__ float csh[CB_CODES][16];
  __shared__ float ccsh[CB_CODES];
  const int tid = threadIdx.x;
  const int r0 = blockIdx.x * 1024 + tid;
  const int c0 = blockIdx.y * CB_CODES;

  {
    int ci = tid >> 1, half = tid & 1;
    const float4* src = reinterpret_cast<const float4*>(cb + (size_t)(c0 + ci) * 16 + half * 8);
    float4 v0 = src[0], v1 = src[1];
    float4* dst = reinterpret_cast<float4*>(&csh[ci][half * 8]);
    dst[0] = v0; dst[1] = v1;
    if (tid < CB_CODES) {
      const float4* p = reinterpret_cast<const float4*>(cb + (size_t)(c0 + tid) * 16);
      float4 a = p[0], b = p[1], d = p[2], e = p[3];
      ccsh[tid] = a.x*a.x + a.y*a.y + a.z*a.z + a.w*a.w
                + b.x*b.x + b.y*b.y + b.z*b.z + b.w*b.w
                + d.x*d.x + d.y*d.y + d.z*d.z + d.w*d.w
                + e.x*e.x + e.y*e.y + e.z*e.z + e.w*e.w;
    }
  }
  float4 fa[4][4];
  #pragma unroll
  for (int q = 0; q < 4; ++q) {
    const float4* fp = reinterpret_cast<const float4*>(fnorm + (size_t)(r0 + q * 256) * 16);
    fa[q][0] = fp[0]; fa[q][1] = fp[1]; fa[q][2] = fp[2]; fa[q][3] = fp[3];
  }
  __syncthreads();

  float best[4] = {3.4e38f, 3.4e38f, 3.4e38f, 3.4e38f};
  int bidx[4] = {0, 0, 0, 0};
  #pragma unroll 2
  for (int ci = 0; ci < CB_CODES; ++ci) {
    const float4* cvp = reinterpret_cast<const float4*>(&csh[ci][0]);
    float4 c0v = cvp[0], c1v = cvp[1], c2v = cvp[2], c3v = cvp[3];
    float ccv = ccsh[ci];
    #pragma unroll
    for (int q = 0; q < 4; ++q) {
      float dot = fa[q][0].x*c0v.x + fa[q][0].y*c0v.y + fa[q][0].z*c0v.z + fa[q][0].w*c0v.w
                + fa[q][1].x*c1v.x + fa[q][1].y*c1v.y + fa[q][1].z*c1v.z + fa[q][1].w*c1v.w
                + fa[q][2].x*c2v.x + fa[q][2].y*c2v.y + fa[q][2].z*c2v.z + fa[q][2].w*c2v.w
                + fa[q][3].x*c3v.x + fa[q][3].y*c3v.y + fa[q][3].z*c3v.z + fa[q][3].w*c3v.w;
      float d = fmaf(-2.f, dot, ccv);
      if (d < best[q]) { best[q] = d; bidx[q] = c0 + ci; }
    }
  }
  #pragma unroll
  for (int q = 0; q < 4; ++q) {
    pval[(size_t)blockIdx.y * MROWS + r0 + q * 256] = best[q];
    pidx[(size_t)blockIdx.y * MROWS + r0 + q * 256] = bidx[q];
  }
}

// merge partials; also zero rowsum
__global__ void merge_targets_kernel(const float* __restrict__ pval, const int* __restrict__ pidx,
                                     int* __restrict__ targets, float* __restrict__ rowsum) {
  int row = blockIdx.x * 256 + threadIdx.x;
  float best = pval[row]; int bi = pidx[row];
  #pragma unroll 8
  for (int b = 1; b < 64; ++b) {
    float v = pval[(size_t)b * MROWS + row];
    int   i = pidx[(size_t)b * MROWS + row];
    if (v < best) { best = v; bi = i; }
  }
  targets[row] = bi;
  rowsum[row] = 0.f;
}

// ---------------- GEMM (fp8 MFMA) + rowsum(exp); blocks>=4096 do tgt_logit ----------------
#define BM 128
#define BN 128
#define BK 64

__device__ __forceinline__ void gld16(const void* g, void* l3) {
  __builtin_amdgcn_global_load_lds((const __attribute__((address_space(1))) void*)g,
                                   (__attribute__((address_space(3))) void*)l3, 16, 0, 0);
}

__global__ __launch_bounds__(256, 4)
void gemm_ce_kernel(const unsigned char* __restrict__ A,  // [MROWS][KDIM] fp8
                    const unsigned char* __restrict__ B,  // [NCOL][KDIM] fp8 (W^T)
                    const float* __restrict__ bias,
                    float* __restrict__ rowsum,
                    const int* __restrict__ targets,
                    float* __restrict__ tgtlog) {
  __shared__ unsigned char As[BM][BK];   // 8 KB
  __shared__ unsigned char Bs[BN][BK];   // 8 KB
  const int tid = threadIdx.x;
  const int wave = tid >> 6;
  const int lane = tid & 63;
  const int bid = blockIdx.x;

  if (bid >= 4096) {
    // ---- tgt_logit path: tgtlog[r] = A[r].B[tg] + bias[tg] ----
    const int r = (bid - 4096) * 4 + wave;
    const int tg = targets[r];
    uint2 ua = reinterpret_cast<const uint2*>(A + (size_t)r * KDIM)[lane];
    uint2 ub = reinterpret_cast<const uint2*>(B + (size_t)tg * KDIM)[lane];
    float s = 0.f;
    const unsigned char* pa = reinterpret_cast<const unsigned char*>(&ua);
    const unsigned char* pb = reinterpret_cast<const unsigned char*>(&ub);
    #pragma unroll
    for (int i = 0; i < 8; ++i) s += fp82f(pa[i]) * fp82f(pb[i]);
    #pragma unroll
    for (int o = 1; o < 64; o <<= 1) s += __shfl_xor(s, o);
    if (lane == 0) tgtlog[r] = s + bias[tg];
    return;
  }

  // XCD-aware swizzle: each XCD owns 8 bx columns, by-major within.
  const int xcd = bid & 7, idx = bid >> 3;
  const int bx = xcd * 8 + (idx & 7);
  const int by = idx >> 3;
  const int row0 = by * BM;
  const int col0 = bx * BN;
  const int wr = wave >> 1, wc = wave & 1;

  f32x4 acc[4][4];
  #pragma unroll
  for (int i = 0; i < 4; ++i)
    #pragma unroll
    for (int j = 0; j < 4; ++j) acc[i][j] = (f32x4){0.f, 0.f, 0.f, 0.f};

  const int lr = lane >> 2;          // row within 16-row chunk
  const int lc = (lane & 3) * 16;    // 16B col offset within 64B row

  for (int kt = 0; kt < KDIM; kt += BK) {
    // stage: A,B tiles 128x64 fp8; 2 chunks each per wave (chunk = 16 rows x 64B = 1KB)
    #pragma unroll
    for (int c = 0; c < 2; ++c) {
      int rchunk = (wave * 2 + c) * 16;
      gld16(A + (size_t)(row0 + rchunk + lr) * KDIM + kt + lc, &As[rchunk][0]);
      gld16(B + (size_t)(col0 + rchunk + lr) * KDIM + kt + lc, &Bs[rchunk][0]);
    }
    __syncthreads();
    #pragma unroll
    for (int ks = 0; ks < 2; ++ks) {
      const int ke = ks * 32 + (lane >> 4) * 8;
      long af[4], bb[4];
      #pragma unroll
      for (int mi = 0; mi < 4; ++mi)
        af[mi] = *(const long*)&As[wr * 64 + mi * 16 + (lane & 15)][ke];
      #pragma unroll
      for (int ni = 0; ni < 4; ++ni)
        bb[ni] = *(const long*)&Bs[wc * 64 + ni * 16 + (lane & 15)][ke];
      #pragma unroll
      for (int mi = 0; mi < 4; ++mi)
        #pragma unroll
        for (int ni = 0; ni < 4; ++ni)
          acc[mi][ni] = __builtin_amdgcn_mfma_f32_16x16x32_fp8_fp8(af[mi], bb[ni], acc[mi][ni], 0, 0, 0);
    }
    __syncthreads();
  }

  // slim epilogue: per-row partial sum(exp(logit))
  float bv[4];
  #pragma unroll
  for (int ni = 0; ni < 4; ++ni)
    bv[ni] = bias[col0 + wc * 64 + ni * 16 + (lane & 15)];
  #pragma unroll
  for (int mi = 0; mi < 4; ++mi) {
    int rbase = row0 + wr * 64 + mi * 16 + (lane >> 4) * 4;
    #pragma unroll
    for (int j = 0; j < 4; ++j) {
      float se = 0.f;
      #pragma unroll
      for (int ni = 0; ni < 4; ++ni)
        se += __expf(acc[mi][ni][j] + bv[ni]);
      #pragma unroll
      for (int o = 1; o < 16; o <<= 1) se += __shfl_xor(se, o);
      if ((lane & 15) == 0) atomicAdd(&rowsum[rbase + j], se);
    }
  }
}

// ---------------- final masked-mean loss ----------------
__global__ void loss_kernel(const float* __restrict__ rowsum, const float* __restrict__ tgtl,
                            const int* __restrict__ lens, float* __restrict__ out) {
  __shared__ float sh[256];
  __shared__ int shc[256];
  int tid = threadIdx.x;
  float s = 0.f; int c = 0;
  for (int r = tid; r < MROWS; r += 256) {
    int n = r >> 11;
    int t = r & (TSEQ - 1);
    if (t < lens[n]) { s += logf(rowsum[r]) - tgtl[r]; c++; }
  }
  sh[tid] = s; shc[tid] = c;
  __syncthreads();
  for (int o = 128; o > 0; o >>= 1) {
    if (tid < o) { sh[tid] += sh[tid + o]; shc[tid] += shc[tid + o]; }
    __syncthreads();
  }
  if (tid == 0) out[0] = sh[0] / (float)max(shc[0], 1);
}

extern "C" void kernel_launch(void* const* d_in, const int* in_sizes, int n_in,
                              void* d_out, int out_size, void* d_ws, size_t ws_size,
                              hipStream_t stream) {
  const float* feats    = (const float*)d_in[0];
  const float* context  = (const float*)d_in[1];
  const int*   lens     = (const int*)d_in[2];
  const float* proj     = (const float*)d_in[3];
  const float* codebook = (const float*)d_in[4];
  const float* W_enc    = (const float*)d_in[5];
  const float* b_enc    = (const float*)d_in[6];
  float* out = (float*)d_out;

  char* ws = (char*)d_ws;
  unsigned char* A8 = (unsigned char*)(ws);                // 4 MB
  unsigned char* B8 = (unsigned char*)(ws + 4194304);      // 4 MB
  float* pval    = (float*)(ws + 8388608);                 // 2 MB
  int*   pidx    = (int*)  (ws + 10485760);                // 2 MB
  float* fnorm   = (float*)(ws + 12582912);                // 512 KB
  float* rowsum  = (float*)(ws + 13107200);                // 32 KB
  float* tgtlog  = (float*)(ws + 13139968);                // 32 KB
  int*   targets = (int*)  (ws + 13172736);                // 32 KB

  // 1) all input-only prep in one dispatch
  prep_kernel<<<8704, 256, 0, stream>>>(context, A8, W_enc, B8, feats, proj, fnorm);
  // 2) codebook search partials
  {
    dim3 g(MROWS / 1024, NCOL / CB_CODES);   // (8, 64)
    targets_part_kernel<<<g, 256, 0, stream>>>(fnorm, codebook, pval, pidx);
  }
  // 3) merge + zero rowsum
  merge_targets_kernel<<<MROWS / 256, 256, 0, stream>>>(pval, pidx, targets, rowsum);
  // 4) fused GEMM + rowsum(exp) + tgt_logit (extra blocks)
  gemm_ce_kernel<<<4096 + MROWS / 4, 256, 0, stream>>>(A8, B8, b_enc, rowsum, targets, tgtlog);
  // 5) final loss
  loss_kernel<<<1, 256, 0, stream>>>(rowsum, tgtlog, lens, out);
}

// Round 8
// 227.555 us; speedup vs baseline: 1.1688x; 1.1688x over previous
//
#include <hip/hip_runtime.h>
#include <hip/hip_bf16.h>
#include <hip/hip_fp8.h>

#define MROWS 8192   // N*T
#define KDIM  512    // CIN
#define NCOL  8192   // codebook size K
#define TSEQ  2048

typedef float f32x4 __attribute__((ext_vector_type(4)));

__device__ __forceinline__ unsigned int pack4_fp8(float a, float b, float c, float d) {
#if __has_builtin(__builtin_amdgcn_cvt_pk_fp8_f32)
  int r = __builtin_amdgcn_cvt_pk_fp8_f32(a, b, 0, false);
  r = __builtin_amdgcn_cvt_pk_fp8_f32(c, d, r, true);
  return (unsigned int)r;
#else
  __hip_fp8_e4m3 ha(a), hb(b), hc(c), hd(d);
  return (unsigned int)ha.__x | ((unsigned int)hb.__x << 8) |
         ((unsigned int)hc.__x << 16) | ((unsigned int)hd.__x << 24);
#endif
}

// exact OCP e4m3 decode (inverse of encode; NaN never occurs for our data)
__device__ __forceinline__ float fp8d(unsigned char b) {
  unsigned int s = b >> 7, e = (b >> 3) & 15, m = b & 7;
  if (e == 0) {
    float v = (float)m * 0.001953125f;  // m * 2^-9
    return s ? -v : v;
  }
  unsigned int bits = (s << 31) | ((e + 120) << 23) | (m << 20);
  return __uint_as_float(bits);
}

// ---------------- prep: context->fp8, W_enc transpose->fp8, fproj ----------------
// blocks [0,4096): convA   [4096,5120): convB 64x64 tiles   [5120,5632): fproj
__global__ void prep_kernel(const float* __restrict__ X, unsigned char* __restrict__ A8,
                            const float* __restrict__ W, unsigned char* __restrict__ B8,
                            const float* __restrict__ feats, const float* __restrict__ proj,
                            float* __restrict__ fnorm) {
  __shared__ float tile[64][65];
  const int tid = threadIdx.x;
  int b = blockIdx.x;
  if (b < 4096) {
    int i = b * 256 + tid;                 // float4 index
    float4 v = reinterpret_cast<const float4*>(X)[i];
    reinterpret_cast<unsigned int*>(A8)[i] = pack4_fp8(v.x, v.y, v.z, v.w);
  } else if (b < 5120) {
    b -= 4096;
    const int bx = b & 127, by = b >> 7;    // 128 col-tiles x 8 row-tiles (of W)
    const int c4 = tid & 15, rr = tid >> 4; // 16 float4-cols x 16 rows per pass
    #pragma unroll
    for (int p = 0; p < 4; ++p) {
      int row = p * 16 + rr;
      float4 v = reinterpret_cast<const float4*>(W + (size_t)(by * 64 + row) * NCOL + bx * 64)[c4];
      tile[row][c4 * 4 + 0] = v.x; tile[row][c4 * 4 + 1] = v.y;
      tile[row][c4 * 4 + 2] = v.z; tile[row][c4 * 4 + 3] = v.w;
    }
    __syncthreads();
    #pragma unroll
    for (int p = 0; p < 4; ++p) {
      int oc = p * 16 + rr;               // output row (W col)
      unsigned int pk = pack4_fp8(tile[c4 * 4 + 0][oc], tile[c4 * 4 + 1][oc],
                                  tile[c4 * 4 + 2][oc], tile[c4 * 4 + 3][oc]);
      *reinterpret_cast<unsigned int*>(B8 + (size_t)(bx * 64 + oc) * KDIM + by * 64 + c4 * 4) = pk;
    }
  } else {
    b -= 5120;
    int rl = tid >> 4, d = tid & 15;
    int row = b * 16 + rl;
    const float4* fr4 = reinterpret_cast<const float4*>(feats + (size_t)row * KDIM);
    float acc = 0.f;
    #pragma unroll 4
    for (int kc = 0; kc < KDIM / 4; ++kc) {
      float4 v = fr4[kc];
      const float* p = proj + (size_t)kc * 64 + d;
      acc += v.x * p[0] + v.y * p[16] + v.z * p[32] + v.w * p[48];
    }
    float s = acc * acc;
    #pragma unroll
    for (int o = 1; o < 16; o <<= 1) s += __shfl_xor(s, o);
    float nrm = sqrtf(s);
    fnorm[(size_t)row * 16 + d] = acc / fmaxf(nrm, 1e-12f);
  }
}

// ---------------- nearest codebook: 4 rows/thread ----------------
#define CB_CODES 128
__global__ __launch_bounds__(256)
void targets_part_kernel(const float* __restrict__ fnorm, const float* __restrict__ cb,
                         float* __restrict__ pval, int* __restrict__ pidx) {
  __shared__ float csh[CB_CODES][16];
  __shared__ float ccsh[CB_CODES];
  const int tid = threadIdx.x;
  const int r0 = blockIdx.x * 1024 + tid;
  const int c0 = blockIdx.y * CB_CODES;

  {
    int ci = tid >> 1, half = tid & 1;
    const float4* src = reinterpret_cast<const float4*>(cb + (size_t)(c0 + ci) * 16 + half * 8);
    float4 v0 = src[0], v1 = src[1];
    float4* dst = reinterpret_cast<float4*>(&csh[ci][half * 8]);
    dst[0] = v0; dst[1] = v1;
    if (tid < CB_CODES) {
      const float4* p = reinterpret_cast<const float4*>(cb + (size_t)(c0 + tid) * 16);
      float4 a = p[0], b = p[1], d = p[2], e = p[3];
      ccsh[tid] = a.x*a.x + a.y*a.y + a.z*a.z + a.w*a.w
                + b.x*b.x + b.y*b.y + b.z*b.z + b.w*b.w
                + d.x*d.x + d.y*d.y + d.z*d.z + d.w*d.w
                + e.x*e.x + e.y*e.y + e.z*e.z + e.w*e.w;
    }
  }
  float4 fa[4][4];
  #pragma unroll
  for (int q = 0; q < 4; ++q) {
    const float4* fp = reinterpret_cast<const float4*>(fnorm + (size_t)(r0 + q * 256) * 16);
    fa[q][0] = fp[0]; fa[q][1] = fp[1]; fa[q][2] = fp[2]; fa[q][3] = fp[3];
  }
  __syncthreads();

  float best[4] = {3.4e38f, 3.4e38f, 3.4e38f, 3.4e38f};
  int bidx[4] = {0, 0, 0, 0};
  #pragma unroll 2
  for (int ci = 0; ci < CB_CODES; ++ci) {
    const float4* cvp = reinterpret_cast<const float4*>(&csh[ci][0]);
    float4 c0v = cvp[0], c1v = cvp[1], c2v = cvp[2], c3v = cvp[3];
    float ccv = ccsh[ci];
    #pragma unroll
    for (int q = 0; q < 4; ++q) {
      float dot = fa[q][0].x*c0v.x + fa[q][0].y*c0v.y + fa[q][0].z*c0v.z + fa[q][0].w*c0v.w
                + fa[q][1].x*c1v.x + fa[q][1].y*c1v.y + fa[q][1].z*c1v.z + fa[q][1].w*c1v.w
                + fa[q][2].x*c2v.x + fa[q][2].y*c2v.y + fa[q][2].z*c2v.z + fa[q][2].w*c2v.w
                + fa[q][3].x*c3v.x + fa[q][3].y*c3v.y + fa[q][3].z*c3v.z + fa[q][3].w*c3v.w;
      float d = fmaf(-2.f, dot, ccv);
      if (d < best[q]) { best[q] = d; bidx[q] = c0 + ci; }
    }
  }
  #pragma unroll
  for (int q = 0; q < 4; ++q) {
    pval[(size_t)blockIdx.y * MROWS + r0 + q * 256] = best[q];
    pidx[(size_t)blockIdx.y * MROWS + r0 + q * 256] = bidx[q];
  }
}

// merge partials; also zero rowsum
__global__ void merge_targets_kernel(const float* __restrict__ pval, const int* __restrict__ pidx,
                                     int* __restrict__ targets, float* __restrict__ rowsum) {
  int row = blockIdx.x * 256 + threadIdx.x;
  float best = pval[row]; int bi = pidx[row];
  #pragma unroll 8
  for (int b = 1; b < 64; ++b) {
    float v = pval[(size_t)b * MROWS + row];
    int   i = pidx[(size_t)b * MROWS + row];
    if (v < best) { best = v; bi = i; }
  }
  targets[row] = bi;
  rowsum[row] = 0.f;
}

// ---------------- GEMM (fp8 MFMA, T2-swizzled LDS) + rowsum(exp); blocks>=4096 tgt_logit ----------------
#define BM 128
#define BN 128
#define BK 64

__device__ __forceinline__ void gld16(const void* g, void* l3) {
  __builtin_amdgcn_global_load_lds((const __attribute__((address_space(1))) void*)g,
                                   (__attribute__((address_space(3))) void*)l3, 16, 0, 0);
}

__global__ __launch_bounds__(256, 4)
void gemm_ce_kernel(const unsigned char* __restrict__ A,  // [MROWS][KDIM] fp8
                    const unsigned char* __restrict__ B,  // [NCOL][KDIM] fp8 (W^T)
                    const float* __restrict__ bias,
                    float* __restrict__ rowsum,
                    const int* __restrict__ targets,
                    float* __restrict__ tgtlog) {
  __shared__ unsigned char As[BM][BK];   // 8 KB
  __shared__ unsigned char Bs[BN][BK];   // 8 KB
  const int tid = threadIdx.x;
  const int wave = tid >> 6;
  const int lane = tid & 63;
  const int bid = blockIdx.x;

  if (bid >= 4096) {
    // ---- tgt_logit path: tgtlog[r] = A[r].B[tg] + bias[tg] ----
    const int r = (bid - 4096) * 4 + wave;
    const int tg = targets[r];
    uint2 ua = reinterpret_cast<const uint2*>(A + (size_t)r * KDIM)[lane];
    uint2 ub = reinterpret_cast<const uint2*>(B + (size_t)tg * KDIM)[lane];
    float s = 0.f;
    const unsigned char* pa = reinterpret_cast<const unsigned char*>(&ua);
    const unsigned char* pb = reinterpret_cast<const unsigned char*>(&ub);
    #pragma unroll
    for (int i = 0; i < 8; ++i) s += fp8d(pa[i]) * fp8d(pb[i]);
    #pragma unroll
    for (int o = 1; o < 64; o <<= 1) s += __shfl_xor(s, o);
    if (lane == 0) tgtlog[r] = s + bias[tg];
    return;
  }

  // XCD-aware swizzle: each XCD owns 8 bx columns, by-major within.
  const int xcd = bid & 7, idx = bid >> 3;
  const int bx = xcd * 8 + (idx & 7);
  const int by = idx >> 3;
  const int row0 = by * BM;
  const int col0 = bx * BN;
  const int wr = wave >> 1, wc = wave & 1;

  f32x4 acc[4][4];
  #pragma unroll
  for (int i = 0; i < 4; ++i)
    #pragma unroll
    for (int j = 0; j < 4; ++j) acc[i][j] = (f32x4){0.f, 0.f, 0.f, 0.f};

  // staging address pieces: lane -> row (lane>>2) and pre-swizzled 16B slot
  const int lr = lane >> 2;
  const int lc = (((lane & 3) ^ ((lane >> 3) & 3)) << 4);  // inverse-swizzled source col

  // read-side swizzle factor: phys16 = logical16 ^ ((row>>1)&3), row%16 = lane&15
  const int l15 = lane & 15, l16 = lane >> 4;
  const int sw = (l15 >> 1) & 3;
  const int subo = (l16 & 1) * 8;
  const int lg16 = l16 >> 1;                 // logical 16B slot within half-K

  for (int kt = 0; kt < KDIM; kt += BK) {
    #pragma unroll
    for (int c = 0; c < 2; ++c) {
      int rchunk = (wave * 2 + c) * 16;
      gld16(A + (size_t)(row0 + rchunk + lr) * KDIM + kt + lc, &As[rchunk][0]);
      gld16(B + (size_t)(col0 + rchunk + lr) * KDIM + kt + lc, &Bs[rchunk][0]);
    }
    __syncthreads();
    #pragma unroll
    for (int ks = 0; ks < 2; ++ks) {
      const int poff = (((ks * 2 + lg16) ^ sw) << 4) + subo;
      long af[4], bb[4];
      #pragma unroll
      for (int mi = 0; mi < 4; ++mi)
        af[mi] = *(const long*)(&As[0][0] + (wr * 64 + mi * 16 + l15) * 64 + poff);
      #pragma unroll
      for (int ni = 0; ni < 4; ++ni)
        bb[ni] = *(const long*)(&Bs[0][0] + (wc * 64 + ni * 16 + l15) * 64 + poff);
      #pragma unroll
      for (int mi = 0; mi < 4; ++mi)
        #pragma unroll
        for (int ni = 0; ni < 4; ++ni)
          acc[mi][ni] = __builtin_amdgcn_mfma_f32_16x16x32_fp8_fp8(af[mi], bb[ni], acc[mi][ni], 0, 0, 0);
    }
    __syncthreads();
  }

  // slim epilogue: per-row partial sum(exp(logit))
  float bv[4];
  #pragma unroll
  for (int ni = 0; ni < 4; ++ni)
    bv[ni] = bias[col0 + wc * 64 + ni * 16 + l15];
  #pragma unroll
  for (int mi = 0; mi < 4; ++mi) {
    int rbase = row0 + wr * 64 + mi * 16 + l16 * 4;
    #pragma unroll
    for (int j = 0; j < 4; ++j) {
      float se = 0.f;
      #pragma unroll
      for (int ni = 0; ni < 4; ++ni)
        se += __expf(acc[mi][ni][j] + bv[ni]);
      #pragma unroll
      for (int o = 1; o < 16; o <<= 1) se += __shfl_xor(se, o);
      if (l15 == 0) atomicAdd(&rowsum[rbase + j], se);
    }
  }
}

// ---------------- final masked-mean loss ----------------
__global__ void loss_kernel(const float* __restrict__ rowsum, const float* __restrict__ tgtl,
                            const int* __restrict__ lens, float* __restrict__ out) {
  __shared__ float sh[256];
  __shared__ int shc[256];
  int tid = threadIdx.x;
  float s = 0.f; int c = 0;
  for (int r = tid; r < MROWS; r += 256) {
    int n = r >> 11;
    int t = r & (TSEQ - 1);
    if (t < lens[n]) { s += logf(rowsum[r]) - tgtl[r]; c++; }
  }
  sh[tid] = s; shc[tid] = c;
  __syncthreads();
  for (int o = 128; o > 0; o >>= 1) {
    if (tid < o) { sh[tid] += sh[tid + o]; shc[tid] += shc[tid + o]; }
    __syncthreads();
  }
  if (tid == 0) out[0] = sh[0] / (float)max(shc[0], 1);
}

extern "C" void kernel_launch(void* const* d_in, const int* in_sizes, int n_in,
                              void* d_out, int out_size, void* d_ws, size_t ws_size,
                              hipStream_t stream) {
  const float* feats    = (const float*)d_in[0];
  const float* context  = (const float*)d_in[1];
  const int*   lens     = (const int*)d_in[2];
  const float* proj     = (const float*)d_in[3];
  const float* codebook = (const float*)d_in[4];
  const float* W_enc    = (const float*)d_in[5];
  const float* b_enc    = (const float*)d_in[6];
  float* out = (float*)d_out;

  char* ws = (char*)d_ws;
  unsigned char* A8 = (unsigned char*)(ws);                // 4 MB
  unsigned char* B8 = (unsigned char*)(ws + 4194304);      // 4 MB
  float* pval    = (float*)(ws + 8388608);                 // 2 MB
  int*   pidx    = (int*)  (ws + 10485760);                // 2 MB
  float* fnorm   = (float*)(ws + 12582912);                // 512 KB
  float* rowsum  = (float*)(ws + 13107200);                // 32 KB
  float* tgtlog  = (float*)(ws + 13139968);                // 32 KB
  int*   targets = (int*)  (ws + 13172736);                // 32 KB

  // 1) all input-only prep in one dispatch
  prep_kernel<<<5632, 256, 0, stream>>>(context, A8, W_enc, B8, feats, proj, fnorm);
  // 2) codebook search partials
  {
    dim3 g(MROWS / 1024, NCOL / CB_CODES);   // (8, 64)
    targets_part_kernel<<<g, 256, 0, stream>>>(fnorm, codebook, pval, pidx);
  }
  // 3) merge + zero rowsum
  merge_targets_kernel<<<MROWS / 256, 256, 0, stream>>>(pval, pidx, targets, rowsum);
  // 4) fused GEMM + rowsum(exp) + tgt_logit (extra blocks)
  gemm_ce_kernel<<<4096 + MROWS / 4, 256, 0, stream>>>(A8, B8, b_enc, rowsum, targets, tgtlog);
  // 5) final loss
  loss_kernel<<<1, 256, 0, stream>>>(rowsum, tgtlog, lens, out);
}

// Round 9
// 196.463 us; speedup vs baseline: 1.3537x; 1.1583x over previous
//
#include <hip/hip_runtime.h>
#include <hip/hip_bf16.h>
#include <hip/hip_fp8.h>

#define MROWS 8192   // N*T
#define KDIM  512    // CIN
#define NCOL  8192   // codebook size K
#define TSEQ  2048

typedef float f32x4 __attribute__((ext_vector_type(4)));

__device__ __forceinline__ unsigned int pack4_fp8(float a, float b, float c, float d) {
#if __has_builtin(__builtin_amdgcn_cvt_pk_fp8_f32)
  int r = __builtin_amdgcn_cvt_pk_fp8_f32(a, b, 0, false);
  r = __builtin_amdgcn_cvt_pk_fp8_f32(c, d, r, true);
  return (unsigned int)r;
#else
  __hip_fp8_e4m3 ha(a), hb(b), hc(c), hd(d);
  return (unsigned int)ha.__x | ((unsigned int)hb.__x << 8) |
         ((unsigned int)hc.__x << 16) | ((unsigned int)hd.__x << 24);
#endif
}

// exact OCP e4m3 decode
__device__ __forceinline__ float fp8d(unsigned char b) {
  unsigned int s = b >> 7, e = (b >> 3) & 15, m = b & 7;
  if (e == 0) {
    float v = (float)m * 0.001953125f;
    return s ? -v : v;
  }
  unsigned int bits = (s << 31) | ((e + 120) << 23) | (m << 20);
  return __uint_as_float(bits);
}

// ---------------- prep: convA, convB-transpose, fproj (no normalize), init ----------------
// [0,4096): convA   [4096,5120): convB   [5120,5632): fproj   [5632,5664): init amin/rowsum
__global__ void prep_kernel(const float* __restrict__ X, unsigned char* __restrict__ A8,
                            const float* __restrict__ W, unsigned char* __restrict__ B8,
                            const float* __restrict__ feats, const float* __restrict__ proj,
                            float* __restrict__ F, unsigned long long* __restrict__ amin,
                            float* __restrict__ rowsum) {
  __shared__ float tile[64][65];
  const int tid = threadIdx.x;
  int b = blockIdx.x;
  if (b < 4096) {
    int i = b * 256 + tid;                 // float4 index
    float4 v = reinterpret_cast<const float4*>(X)[i];
    reinterpret_cast<unsigned int*>(A8)[i] = pack4_fp8(v.x, v.y, v.z, v.w);
  } else if (b < 5120) {
    b -= 4096;
    const int bx = b & 127, by = b >> 7;    // 128 col-tiles x 8 row-tiles of W
    const int c4 = tid & 15, rr = tid >> 4;
    #pragma unroll
    for (int p = 0; p < 4; ++p) {
      int row = p * 16 + rr;
      float4 v = reinterpret_cast<const float4*>(W + (size_t)(by * 64 + row) * NCOL + bx * 64)[c4];
      tile[row][c4 * 4 + 0] = v.x; tile[row][c4 * 4 + 1] = v.y;
      tile[row][c4 * 4 + 2] = v.z; tile[row][c4 * 4 + 3] = v.w;
    }
    __syncthreads();
    #pragma unroll
    for (int p = 0; p < 4; ++p) {
      int oc = p * 16 + rr;               // output row (W col)
      unsigned int pk = pack4_fp8(tile[c4 * 4 + 0][oc], tile[c4 * 4 + 1][oc],
                                  tile[c4 * 4 + 2][oc], tile[c4 * 4 + 3][oc]);
      *reinterpret_cast<unsigned int*>(B8 + (size_t)(bx * 64 + oc) * KDIM + by * 64 + c4 * 4) = pk;
    }
  } else if (b < 5632) {
    b -= 5120;
    int rl = tid >> 4, d = tid & 15;
    int row = b * 16 + rl;
    const float4* fr4 = reinterpret_cast<const float4*>(feats + (size_t)row * KDIM);
    float acc = 0.f;
    #pragma unroll 4
    for (int kc = 0; kc < KDIM / 4; ++kc) {
      float4 v = fr4[kc];
      const float* p = proj + (size_t)kc * 64 + d;
      acc += v.x * p[0] + v.y * p[16] + v.z * p[32] + v.w * p[48];
    }
    F[(size_t)row * 16 + d] = acc;        // unnormalized: argmax dot == ref argmin
  } else {
    int r = (b - 5632) * 256 + tid;
    amin[r] = ~0ull;
    rowsum[r] = 0.f;
  }
}

// ---------------- fused: GEMM (fp8, BK=128) + codebook-argmax (extra blocks) ----------------
#define GEMM_BLOCKS 4096
#define CB_CODES 128

__device__ __forceinline__ void gld16(const void* g, void* l3) {
  __builtin_amdgcn_global_load_lds((const __attribute__((address_space(1))) void*)g,
                                   (__attribute__((address_space(3))) void*)l3, 16, 0, 0);
}

__global__ __launch_bounds__(256, 4)
void gemm_targets_kernel(const unsigned char* __restrict__ A,  // [MROWS][KDIM] fp8
                         const unsigned char* __restrict__ B,  // [NCOL][KDIM] fp8 (W^T)
                         const float* __restrict__ bias,
                         float* __restrict__ rowsum,
                         const float* __restrict__ F,
                         const float* __restrict__ cb,
                         unsigned long long* __restrict__ amin) {
  __shared__ __align__(16) unsigned char smem[32768];
  const int tid = threadIdx.x;
  const int bid = blockIdx.x;

  if (bid >= GEMM_BLOCKS) {
    // ---- targets path: block owns 1024 rows x 128 codes; u64 atomicMin merge ----
    float (*csh)[16] = (float (*)[16])smem;
    const int tb = bid - GEMM_BLOCKS;
    const int r0 = (tb & 7) * 1024 + tid;
    const int c0 = (tb >> 3) * CB_CODES;
    {
      int ci = tid >> 1, half = tid & 1;
      const float4* src = reinterpret_cast<const float4*>(cb + (size_t)(c0 + ci) * 16 + half * 8);
      float4 v0 = src[0], v1 = src[1];
      float4* dst = reinterpret_cast<float4*>(&csh[ci][half * 8]);
      dst[0] = v0; dst[1] = v1;
    }
    float4 fa[4][4];
    #pragma unroll
    for (int q = 0; q < 4; ++q) {
      const float4* fp = reinterpret_cast<const float4*>(F + (size_t)(r0 + q * 256) * 16);
      fa[q][0] = fp[0]; fa[q][1] = fp[1]; fa[q][2] = fp[2]; fa[q][3] = fp[3];
    }
    __syncthreads();

    float best[4] = {3.4e38f, 3.4e38f, 3.4e38f, 3.4e38f};
    int bidx[4] = {0, 0, 0, 0};
    #pragma unroll 2
    for (int ci = 0; ci < CB_CODES; ++ci) {
      const float4* cvp = reinterpret_cast<const float4*>(&csh[ci][0]);
      float4 c0v = cvp[0], c1v = cvp[1], c2v = cvp[2], c3v = cvp[3];
      #pragma unroll
      for (int q = 0; q < 4; ++q) {
        float dot = fa[q][0].x*c0v.x + fa[q][0].y*c0v.y + fa[q][0].z*c0v.z + fa[q][0].w*c0v.w
                  + fa[q][1].x*c1v.x + fa[q][1].y*c1v.y + fa[q][1].z*c1v.z + fa[q][1].w*c1v.w
                  + fa[q][2].x*c2v.x + fa[q][2].y*c2v.y + fa[q][2].z*c2v.z + fa[q][2].w*c2v.w
                  + fa[q][3].x*c3v.x + fa[q][3].y*c3v.y + fa[q][3].z*c3v.z + fa[q][3].w*c3v.w;
        float d = -dot;
        if (d < best[q]) { best[q] = d; bidx[q] = c0 + ci; }
      }
    }
    #pragma unroll
    for (int q = 0; q < 4; ++q) {
      unsigned int u = __float_as_uint(best[q]);
      unsigned int key = (u & 0x80000000u) ? ~u : (u | 0x80000000u);  // order-preserving
      unsigned long long pk = ((unsigned long long)key << 32) | (unsigned int)bidx[q];
      atomicMin(&amin[r0 + q * 256], pk);
    }
    return;
  }

  // ---- gemm path: 128x128 tile, BK=128 (two 64B K-planes per operand) ----
  const int wave = tid >> 6;
  const int lane = tid & 63;
  const int xcd = bid & 7, idx = bid >> 3;
  const int bx = xcd * 8 + (idx & 7);
  const int by = idx >> 3;
  const int row0 = by * 128;
  const int col0 = bx * 128;
  const int wr = wave >> 1, wc = wave & 1;
  unsigned char* As = smem;            // [2 planes][128 rows][64B]
  unsigned char* Bs = smem + 16384;

  f32x4 acc[4][4];
  #pragma unroll
  for (int i = 0; i < 4; ++i)
    #pragma unroll
    for (int j = 0; j < 4; ++j) acc[i][j] = (f32x4){0.f, 0.f, 0.f, 0.f};

  const int lr = lane >> 2;                               // 16 rows per gld16
  const int lcs = (((lane & 3) ^ ((lane >> 3) & 3)) << 4);// pre-swizzled src 16B slot

  const int l15 = lane & 15, l16 = lane >> 4;
  const int sw = (l15 >> 1) & 3;
  const int subo = (l16 & 1) * 8;
  const int lg16 = l16 >> 1;

  for (int kt = 0; kt < KDIM; kt += 128) {
    #pragma unroll
    for (int c = 0; c < 2; ++c) {
      int rchunk = (wave * 2 + c) * 16;
      #pragma unroll
      for (int kp = 0; kp < 2; ++kp) {
        gld16(A + (size_t)(row0 + rchunk + lr) * KDIM + kt + kp * 64 + lcs,
              As + kp * 8192 + rchunk * 64);
        gld16(B + (size_t)(col0 + rchunk + lr) * KDIM + kt + kp * 64 + lcs,
              Bs + kp * 8192 + rchunk * 64);
      }
    }
    __syncthreads();
    #pragma unroll
    for (int ks = 0; ks < 4; ++ks) {
      const int kpl = (ks >> 1) * 8192;
      const int poff = ((((ks & 1) * 2 + lg16) ^ sw) << 4) + subo;
      long af[4], bb[4];
      #pragma unroll
      for (int mi = 0; mi < 4; ++mi)
        af[mi] = *(const long*)(As + kpl + (wr * 64 + mi * 16 + l15) * 64 + poff);
      #pragma unroll
      for (int ni = 0; ni < 4; ++ni)
        bb[ni] = *(const long*)(Bs + kpl + (wc * 64 + ni * 16 + l15) * 64 + poff);
      #pragma unroll
      for (int mi = 0; mi < 4; ++mi)
        #pragma unroll
        for (int ni = 0; ni < 4; ++ni)
          acc[mi][ni] = __builtin_amdgcn_mfma_f32_16x16x32_fp8_fp8(af[mi], bb[ni], acc[mi][ni], 0, 0, 0);
    }
    __syncthreads();
  }

  // slim epilogue: per-row partial sum(exp(logit))
  float bv[4];
  #pragma unroll
  for (int ni = 0; ni < 4; ++ni)
    bv[ni] = bias[col0 + wc * 64 + ni * 16 + l15];
  #pragma unroll
  for (int mi = 0; mi < 4; ++mi) {
    int rbase = row0 + wr * 64 + mi * 16 + l16 * 4;
    #pragma unroll
    for (int j = 0; j < 4; ++j) {
      float se = 0.f;
      #pragma unroll
      for (int ni = 0; ni < 4; ++ni)
        se += __expf(acc[mi][ni][j] + bv[ni]);
      #pragma unroll
      for (int o = 1; o < 16; o <<= 1) se += __shfl_xor(se, o);
      if (l15 == 0) atomicAdd(&rowsum[rbase + j], se);
    }
  }
}

// ---------------- target logit: tgtlog[r] = A[r].B[tg] + bias[tg] ----------------
__global__ void tgt_logit_kernel(const unsigned char* __restrict__ A,
                                 const unsigned char* __restrict__ B,
                                 const float* __restrict__ bias,
                                 const unsigned long long* __restrict__ amin,
                                 float* __restrict__ tgtlog) {
  const int wv = threadIdx.x >> 6, lane = threadIdx.x & 63;
  const int r = blockIdx.x * 4 + wv;
  const int tg = (int)(amin[r] & 0xffffffffull);
  uint2 ua = reinterpret_cast<const uint2*>(A + (size_t)r * KDIM)[lane];
  uint2 ub = reinterpret_cast<const uint2*>(B + (size_t)tg * KDIM)[lane];
  float s = 0.f;
  const unsigned char* pa = reinterpret_cast<const unsigned char*>(&ua);
  const unsigned char* pb = reinterpret_cast<const unsigned char*>(&ub);
  #pragma unroll
  for (int i = 0; i < 8; ++i) s += fp8d(pa[i]) * fp8d(pb[i]);
  #pragma unroll
  for (int o = 1; o < 64; o <<= 1) s += __shfl_xor(s, o);
  if (lane == 0) tgtlog[r] = s + bias[tg];
}

// ---------------- final masked-mean loss ----------------
__global__ void loss_kernel(const float* __restrict__ rowsum, const float* __restrict__ tgtl,
                            const int* __restrict__ lens, float* __restrict__ out) {
  __shared__ float sh[256];
  __shared__ int shc[256];
  int tid = threadIdx.x;
  float s = 0.f; int c = 0;
  for (int r = tid; r < MROWS; r += 256) {
    int n = r >> 11;
    int t = r & (TSEQ - 1);
    if (t < lens[n]) { s += logf(rowsum[r]) - tgtl[r]; c++; }
  }
  sh[tid] = s; shc[tid] = c;
  __syncthreads();
  for (int o = 128; o > 0; o >>= 1) {
    if (tid < o) { sh[tid] += sh[tid + o]; shc[tid] += shc[tid + o]; }
    __syncthreads();
  }
  if (tid == 0) out[0] = sh[0] / (float)max(shc[0], 1);
}

extern "C" void kernel_launch(void* const* d_in, const int* in_sizes, int n_in,
                              void* d_out, int out_size, void* d_ws, size_t ws_size,
                              hipStream_t stream) {
  const float* feats    = (const float*)d_in[0];
  const float* context  = (const float*)d_in[1];
  const int*   lens     = (const int*)d_in[2];
  const float* proj     = (const float*)d_in[3];
  const float* codebook = (const float*)d_in[4];
  const float* W_enc    = (const float*)d_in[5];
  const float* b_enc    = (const float*)d_in[6];
  float* out = (float*)d_out;

  char* ws = (char*)d_ws;
  unsigned char* A8 = (unsigned char*)(ws);                       // 4 MB
  unsigned char* B8 = (unsigned char*)(ws + 4194304);             // 4 MB
  float* F          = (float*)(ws + 8388608);                     // 512 KB
  unsigned long long* amin = (unsigned long long*)(ws + 8912896); // 64 KB
  float* rowsum     = (float*)(ws + 8978432);                     // 32 KB
  float* tgtlog     = (float*)(ws + 9011200);                     // 32 KB

  // 1) conversions + projection + init
  prep_kernel<<<5664, 256, 0, stream>>>(context, A8, W_enc, B8, feats, proj, F, amin, rowsum);
  // 2) GEMM+rowsum(exp)  ||  codebook argmax (independent work, one dispatch)
  gemm_targets_kernel<<<GEMM_BLOCKS + 512, 256, 0, stream>>>(A8, B8, b_enc, rowsum, F, codebook, amin);
  // 3) target logit
  tgt_logit_kernel<<<MROWS / 4, 256, 0, stream>>>(A8, B8, b_enc, amin, tgtlog);
  // 4) final loss
  loss_kernel<<<1, 256, 0, stream>>>(rowsum, tgtlog, lens, out);
}

// Round 10
// 190.744 us; speedup vs baseline: 1.3943x; 1.0300x over previous
//
#include <hip/hip_runtime.h>
#include <hip/hip_bf16.h>
#include <hip/hip_fp8.h>

#define MROWS 8192   // N*T
#define KDIM  512    // CIN
#define NCOL  8192   // codebook size K
#define TSEQ  2048

typedef float f32x4 __attribute__((ext_vector_type(4)));

__device__ __forceinline__ unsigned int pack4_fp8(float a, float b, float c, float d) {
#if __has_builtin(__builtin_amdgcn_cvt_pk_fp8_f32)
  int r = __builtin_amdgcn_cvt_pk_fp8_f32(a, b, 0, false);
  r = __builtin_amdgcn_cvt_pk_fp8_f32(c, d, r, true);
  return (unsigned int)r;
#else
  __hip_fp8_e4m3 ha(a), hb(b), hc(c), hd(d);
  return (unsigned int)ha.__x | ((unsigned int)hb.__x << 8) |
         ((unsigned int)hc.__x << 16) | ((unsigned int)hd.__x << 24);
#endif
}

// exact OCP e4m3 decode
__device__ __forceinline__ float fp8d(unsigned char b) {
  unsigned int s = b >> 7, e = (b >> 3) & 15, m = b & 7;
  if (e == 0) {
    float v = (float)m * 0.001953125f;
    return s ? -v : v;
  }
  unsigned int bits = (s << 31) | ((e + 120) << 23) | (m << 20);
  return __uint_as_float(bits);
}

// ---------------- prep: convA, convB-transpose, fproj (no normalize), init ----------------
// [0,4096): convA   [4096,5120): convB   [5120,5632): fproj   [5632,5664): init amin/rowsum
__global__ void prep_kernel(const float* __restrict__ X, unsigned char* __restrict__ A8,
                            const float* __restrict__ W, unsigned char* __restrict__ B8,
                            const float* __restrict__ feats, const float* __restrict__ proj,
                            float* __restrict__ F, unsigned long long* __restrict__ amin,
                            float* __restrict__ rowsum) {
  __shared__ float tile[64][65];
  const int tid = threadIdx.x;
  int b = blockIdx.x;
  if (b < 4096) {
    int i = b * 256 + tid;                 // float4 index
    float4 v = reinterpret_cast<const float4*>(X)[i];
    reinterpret_cast<unsigned int*>(A8)[i] = pack4_fp8(v.x, v.y, v.z, v.w);
  } else if (b < 5120) {
    b -= 4096;
    const int bx = b & 127, by = b >> 7;    // 128 col-tiles x 8 row-tiles of W
    const int c4 = tid & 15, rr = tid >> 4;
    #pragma unroll
    for (int p = 0; p < 4; ++p) {
      int row = p * 16 + rr;
      float4 v = reinterpret_cast<const float4*>(W + (size_t)(by * 64 + row) * NCOL + bx * 64)[c4];
      tile[row][c4 * 4 + 0] = v.x; tile[row][c4 * 4 + 1] = v.y;
      tile[row][c4 * 4 + 2] = v.z; tile[row][c4 * 4 + 3] = v.w;
    }
    __syncthreads();
    #pragma unroll
    for (int p = 0; p < 4; ++p) {
      int oc = p * 16 + rr;               // output row (W col)
      unsigned int pk = pack4_fp8(tile[c4 * 4 + 0][oc], tile[c4 * 4 + 1][oc],
                                  tile[c4 * 4 + 2][oc], tile[c4 * 4 + 3][oc]);
      *reinterpret_cast<unsigned int*>(B8 + (size_t)(bx * 64 + oc) * KDIM + by * 64 + c4 * 4) = pk;
    }
  } else if (b < 5632) {
    b -= 5120;
    int rl = tid >> 4, d = tid & 15;
    int row = b * 16 + rl;
    const float4* fr4 = reinterpret_cast<const float4*>(feats + (size_t)row * KDIM);
    float acc = 0.f;
    #pragma unroll 4
    for (int kc = 0; kc < KDIM / 4; ++kc) {
      float4 v = fr4[kc];
      const float* p = proj + (size_t)kc * 64 + d;
      acc += v.x * p[0] + v.y * p[16] + v.z * p[32] + v.w * p[48];
    }
    F[(size_t)row * 16 + d] = acc;        // unnormalized: argmax dot == ref argmin
  } else {
    int r = (b - 5632) * 256 + tid;
    amin[r] = ~0ull;
    rowsum[r] = 0.f;
  }
}

// ---------------- fused: codebook-argmax (first 512 blocks) + GEMM (fp8, BK=64) ----------------
#define TGT_BLOCKS 512
#define CB_CODES 128

__device__ __forceinline__ void gld16(const void* g, void* l3) {
  __builtin_amdgcn_global_load_lds((const __attribute__((address_space(1))) void*)g,
                                   (__attribute__((address_space(3))) void*)l3, 16, 0, 0);
}

__global__ __launch_bounds__(256, 4)
void gemm_targets_kernel(const unsigned char* __restrict__ A,  // [MROWS][KDIM] fp8
                         const unsigned char* __restrict__ B,  // [NCOL][KDIM] fp8 (W^T)
                         const float* __restrict__ bias,
                         float* __restrict__ rowsum,
                         const float* __restrict__ F,
                         const float* __restrict__ cb,
                         unsigned long long* __restrict__ amin) {
  __shared__ __align__(16) unsigned char smem[16384];
  const int tid = threadIdx.x;
  const int bid = blockIdx.x;

  if (bid < TGT_BLOCKS) {
    // ---- targets path: block owns 1024 rows x 128 codes; u64 atomicMin merge ----
    float (*csh)[16] = (float (*)[16])smem;
    const int r0 = (bid & 7) * 1024 + tid;
    const int c0 = (bid >> 3) * CB_CODES;
    {
      int ci = tid >> 1, half = tid & 1;
      const float4* src = reinterpret_cast<const float4*>(cb + (size_t)(c0 + ci) * 16 + half * 8);
      float4 v0 = src[0], v1 = src[1];
      float4* dst = reinterpret_cast<float4*>(&csh[ci][half * 8]);
      dst[0] = v0; dst[1] = v1;
    }
    float4 fa[4][4];
    #pragma unroll
    for (int q = 0; q < 4; ++q) {
      const float4* fp = reinterpret_cast<const float4*>(F + (size_t)(r0 + q * 256) * 16);
      fa[q][0] = fp[0]; fa[q][1] = fp[1]; fa[q][2] = fp[2]; fa[q][3] = fp[3];
    }
    __syncthreads();

    float best[4] = {3.4e38f, 3.4e38f, 3.4e38f, 3.4e38f};
    int bidx[4] = {0, 0, 0, 0};
    #pragma unroll 2
    for (int ci = 0; ci < CB_CODES; ++ci) {
      const float4* cvp = reinterpret_cast<const float4*>(&csh[ci][0]);
      float4 c0v = cvp[0], c1v = cvp[1], c2v = cvp[2], c3v = cvp[3];
      #pragma unroll
      for (int q = 0; q < 4; ++q) {
        float dot = fa[q][0].x*c0v.x + fa[q][0].y*c0v.y + fa[q][0].z*c0v.z + fa[q][0].w*c0v.w
                  + fa[q][1].x*c1v.x + fa[q][1].y*c1v.y + fa[q][1].z*c1v.z + fa[q][1].w*c1v.w
                  + fa[q][2].x*c2v.x + fa[q][2].y*c2v.y + fa[q][2].z*c2v.z + fa[q][2].w*c2v.w
                  + fa[q][3].x*c3v.x + fa[q][3].y*c3v.y + fa[q][3].z*c3v.z + fa[q][3].w*c3v.w;
        float d = -dot;
        if (d < best[q]) { best[q] = d; bidx[q] = c0 + ci; }
      }
    }
    #pragma unroll
    for (int q = 0; q < 4; ++q) {
      unsigned int u = __float_as_uint(best[q]);
      unsigned int key = (u & 0x80000000u) ? ~u : (u | 0x80000000u);  // order-preserving
      unsigned long long pk = ((unsigned long long)key << 32) | (unsigned int)bidx[q];
      atomicMin(&amin[r0 + q * 256], pk);
    }
    return;
  }

  // ---- gemm path: 128x128 tile, BK=64 (R8 measured config) ----
  const int gid = bid - TGT_BLOCKS;
  const int wave = tid >> 6;
  const int lane = tid & 63;
  const int xcd = gid & 7, idx = gid >> 3;
  const int bx = xcd * 8 + (idx & 7);
  const int by = idx >> 3;
  const int row0 = by * 128;
  const int col0 = bx * 128;
  const int wr = wave >> 1, wc = wave & 1;
  unsigned char* As = smem;            // [128 rows][64B]
  unsigned char* Bs = smem + 8192;

  f32x4 acc[4][4];
  #pragma unroll
  for (int i = 0; i < 4; ++i)
    #pragma unroll
    for (int j = 0; j < 4; ++j) acc[i][j] = (f32x4){0.f, 0.f, 0.f, 0.f};

  const int lr = lane >> 2;                               // 16 rows per gld16
  const int lcs = (((lane & 3) ^ ((lane >> 3) & 3)) << 4);// pre-swizzled src 16B slot

  const int l15 = lane & 15, l16 = lane >> 4;
  const int sw = (l15 >> 1) & 3;
  const int subo = (l16 & 1) * 8;
  const int lg16 = l16 >> 1;

  for (int kt = 0; kt < KDIM; kt += 64) {
    #pragma unroll
    for (int c = 0; c < 2; ++c) {
      int rchunk = (wave * 2 + c) * 16;
      gld16(A + (size_t)(row0 + rchunk + lr) * KDIM + kt + lcs, As + rchunk * 64);
      gld16(B + (size_t)(col0 + rchunk + lr) * KDIM + kt + lcs, Bs + rchunk * 64);
    }
    __syncthreads();
    #pragma unroll
    for (int ks = 0; ks < 2; ++ks) {
      const int poff = (((ks * 2 + lg16) ^ sw) << 4) + subo;
      long af[4], bb[4];
      #pragma unroll
      for (int mi = 0; mi < 4; ++mi)
        af[mi] = *(const long*)(As + (wr * 64 + mi * 16 + l15) * 64 + poff);
      #pragma unroll
      for (int ni = 0; ni < 4; ++ni)
        bb[ni] = *(const long*)(Bs + (wc * 64 + ni * 16 + l15) * 64 + poff);
      #pragma unroll
      for (int mi = 0; mi < 4; ++mi)
        #pragma unroll
        for (int ni = 0; ni < 4; ++ni)
          acc[mi][ni] = __builtin_amdgcn_mfma_f32_16x16x32_fp8_fp8(af[mi], bb[ni], acc[mi][ni], 0, 0, 0);
    }
    __syncthreads();
  }

  // slim epilogue: per-row partial sum(exp(logit))
  float bv[4];
  #pragma unroll
  for (int ni = 0; ni < 4; ++ni)
    bv[ni] = bias[col0 + wc * 64 + ni * 16 + l15];
  #pragma unroll
  for (int mi = 0; mi < 4; ++mi) {
    int rbase = row0 + wr * 64 + mi * 16 + l16 * 4;
    #pragma unroll
    for (int j = 0; j < 4; ++j) {
      float se = 0.f;
      #pragma unroll
      for (int ni = 0; ni < 4; ++ni)
        se += __expf(acc[mi][ni][j] + bv[ni]);
      #pragma unroll
      for (int o = 1; o < 16; o <<= 1) se += __shfl_xor(se, o);
      if (l15 == 0) atomicAdd(&rowsum[rbase + j], se);
    }
  }
}

// ---------------- target logit: tgtlog[r] = A[r].B[tg] + bias[tg] ----------------
__global__ void tgt_logit_kernel(const unsigned char* __restrict__ A,
                                 const unsigned char* __restrict__ B,
                                 const float* __restrict__ bias,
                                 const unsigned long long* __restrict__ amin,
                                 float* __restrict__ tgtlog) {
  const int wv = threadIdx.x >> 6, lane = threadIdx.x & 63;
  const int r = blockIdx.x * 4 + wv;
  const int tg = (int)(amin[r] & 0xffffffffull);
  uint2 ua = reinterpret_cast<const uint2*>(A + (size_t)r * KDIM)[lane];
  uint2 ub = reinterpret_cast<const uint2*>(B + (size_t)tg * KDIM)[lane];
  float s = 0.f;
  const unsigned char* pa = reinterpret_cast<const unsigned char*>(&ua);
  const unsigned char* pb = reinterpret_cast<const unsigned char*>(&ub);
  #pragma unroll
  for (int i = 0; i < 8; ++i) s += fp8d(pa[i]) * fp8d(pb[i]);
  #pragma unroll
  for (int o = 1; o < 64; o <<= 1) s += __shfl_xor(s, o);
  if (lane == 0) tgtlog[r] = s + bias[tg];
}

// ---------------- final masked-mean loss ----------------
__global__ void loss_kernel(const float* __restrict__ rowsum, const float* __restrict__ tgtl,
                            const int* __restrict__ lens, float* __restrict__ out) {
  __shared__ float sh[256];
  __shared__ int shc[256];
  int tid = threadIdx.x;
  float s = 0.f; int c = 0;
  for (int r = tid; r < MROWS; r += 256) {
    int n = r >> 11;
    int t = r & (TSEQ - 1);
    if (t < lens[n]) { s += logf(rowsum[r]) - tgtl[r]; c++; }
  }
  sh[tid] = s; shc[tid] = c;
  __syncthreads();
  for (int o = 128; o > 0; o >>= 1) {
    if (tid < o) { sh[tid] += sh[tid + o]; shc[tid] += shc[tid + o]; }
    __syncthreads();
  }
  if (tid == 0) out[0] = sh[0] / (float)max(shc[0], 1);
}

extern "C" void kernel_launch(void* const* d_in, const int* in_sizes, int n_in,
                              void* d_out, int out_size, void* d_ws, size_t ws_size,
                              hipStream_t stream) {
  const float* feats    = (const float*)d_in[0];
  const float* context  = (const float*)d_in[1];
  const int*   lens     = (const int*)d_in[2];
  const float* proj     = (const float*)d_in[3];
  const float* codebook = (const float*)d_in[4];
  const float* W_enc    = (const float*)d_in[5];
  const float* b_enc    = (const float*)d_in[6];
  float* out = (float*)d_out;

  char* ws = (char*)d_ws;
  unsigned char* A8 = (unsigned char*)(ws);                       // 4 MB
  unsigned char* B8 = (unsigned char*)(ws + 4194304);             // 4 MB
  float* F          = (float*)(ws + 8388608);                     // 512 KB
  unsigned long long* amin = (unsigned long long*)(ws + 8912896); // 64 KB
  float* rowsum     = (float*)(ws + 8978432);                     // 32 KB
  float* tgtlog     = (float*)(ws + 9011200);                     // 32 KB

  // 1) conversions + projection + init
  prep_kernel<<<5664, 256, 0, stream>>>(context, A8, W_enc, B8, feats, proj, F, amin, rowsum);
  // 2) codebook argmax (first 512 blocks, overlaps)  ||  GEMM+rowsum(exp)
  gemm_targets_kernel<<<TGT_BLOCKS + 4096, 256, 0, stream>>>(A8, B8, b_enc, rowsum, F, codebook, amin);
  // 3) target logit
  tgt_logit_kernel<<<MROWS / 4, 256, 0, stream>>>(A8, B8, b_enc, amin, tgtlog);
  // 4) final loss
  loss_kernel<<<1, 256, 0, stream>>>(rowsum, tgtlog, lens, out);
}

// Round 11
// 183.450 us; speedup vs baseline: 1.4498x; 1.0398x over previous
//
#include <hip/hip_runtime.h>
#include <hip/hip_bf16.h>
#include <hip/hip_fp8.h>

#define MROWS 8192   // N*T
#define KDIM  512    // CIN
#define NCOL  8192   // codebook size K
#define TSEQ  2048

typedef float f32x4 __attribute__((ext_vector_type(4)));

__device__ __forceinline__ unsigned int pack4_fp8(float a, float b, float c, float d) {
#if __has_builtin(__builtin_amdgcn_cvt_pk_fp8_f32)
  int r = __builtin_amdgcn_cvt_pk_fp8_f32(a, b, 0, false);
  r = __builtin_amdgcn_cvt_pk_fp8_f32(c, d, r, true);
  return (unsigned int)r;
#else
  __hip_fp8_e4m3 ha(a), hb(b), hc(c), hd(d);
  return (unsigned int)ha.__x | ((unsigned int)hb.__x << 8) |
         ((unsigned int)hc.__x << 16) | ((unsigned int)hd.__x << 24);
#endif
}

// exact OCP e4m3 decode
__device__ __forceinline__ float fp8d(unsigned char b) {
  unsigned int s = b >> 7, e = (b >> 3) & 15, m = b & 7;
  if (e == 0) {
    float v = (float)m * 0.001953125f;
    return s ? -v : v;
  }
  unsigned int bits = (s << 31) | ((e + 120) << 23) | (m << 20);
  return __uint_as_float(bits);
}

// ---------------- prep: convA, convB-transpose, fproj (no normalize), init ----------------
// [0,4096): convA   [4096,5120): convB   [5120,5632): fproj   [5632,5664): init amin/rowsum
__global__ void prep_kernel(const float* __restrict__ X, unsigned char* __restrict__ A8,
                            const float* __restrict__ W, unsigned char* __restrict__ B8,
                            const float* __restrict__ feats, const float* __restrict__ proj,
                            float* __restrict__ F, unsigned long long* __restrict__ amin,
                            float* __restrict__ rowsum) {
  __shared__ float tile[64][65];
  const int tid = threadIdx.x;
  int b = blockIdx.x;
  if (b < 4096) {
    int i = b * 256 + tid;                 // float4 index
    float4 v = reinterpret_cast<const float4*>(X)[i];
    reinterpret_cast<unsigned int*>(A8)[i] = pack4_fp8(v.x, v.y, v.z, v.w);
  } else if (b < 5120) {
    b -= 4096;
    const int bx = b & 127, by = b >> 7;    // 128 col-tiles x 8 row-tiles of W
    const int c4 = tid & 15, rr = tid >> 4;
    #pragma unroll
    for (int p = 0; p < 4; ++p) {
      int row = p * 16 + rr;
      float4 v = reinterpret_cast<const float4*>(W + (size_t)(by * 64 + row) * NCOL + bx * 64)[c4];
      tile[row][c4 * 4 + 0] = v.x; tile[row][c4 * 4 + 1] = v.y;
      tile[row][c4 * 4 + 2] = v.z; tile[row][c4 * 4 + 3] = v.w;
    }
    __syncthreads();
    #pragma unroll
    for (int p = 0; p < 4; ++p) {
      int oc = p * 16 + rr;               // output row (W col)
      unsigned int pk = pack4_fp8(tile[c4 * 4 + 0][oc], tile[c4 * 4 + 1][oc],
                                  tile[c4 * 4 + 2][oc], tile[c4 * 4 + 3][oc]);
      *reinterpret_cast<unsigned int*>(B8 + (size_t)(bx * 64 + oc) * KDIM + by * 64 + c4 * 4) = pk;
    }
  } else if (b < 5632) {
    b -= 5120;
    int rl = tid >> 4, d = tid & 15;
    int row = b * 16 + rl;
    const float4* fr4 = reinterpret_cast<const float4*>(feats + (size_t)row * KDIM);
    float acc = 0.f;
    #pragma unroll 4
    for (int kc = 0; kc < KDIM / 4; ++kc) {
      float4 v = fr4[kc];
      const float* p = proj + (size_t)kc * 64 + d;
      acc += v.x * p[0] + v.y * p[16] + v.z * p[32] + v.w * p[48];
    }
    F[(size_t)row * 16 + d] = acc;        // unnormalized: argmax dot == ref argmin
  } else {
    int r = (b - 5632) * 256 + tid;
    amin[r] = ~0ull;
    rowsum[r] = 0.f;
  }
}

// ---------------- fused: codebook-argmax (first 512 blocks) + GEMM (fp8, dbuf BK=64) ----------------
#define TGT_BLOCKS 512
#define CB_CODES 128

__device__ __forceinline__ void gld16(const void* g, void* l3) {
  __builtin_amdgcn_global_load_lds((const __attribute__((address_space(1))) void*)g,
                                   (__attribute__((address_space(3))) void*)l3, 16, 0, 0);
}

__global__ __launch_bounds__(256, 4)
void gemm_targets_kernel(const unsigned char* __restrict__ A,  // [MROWS][KDIM] fp8
                         const unsigned char* __restrict__ B,  // [NCOL][KDIM] fp8 (W^T)
                         const float* __restrict__ bias,
                         float* __restrict__ rowsum,
                         const float* __restrict__ F,
                         const float* __restrict__ cb,
                         unsigned long long* __restrict__ amin) {
  __shared__ __align__(16) unsigned char smem[32768];
  const int tid = threadIdx.x;
  const int bid = blockIdx.x;

  if (bid < TGT_BLOCKS) {
    // ---- targets path: block owns 1024 rows x 128 codes; u64 atomicMin merge ----
    float (*csh)[16] = (float (*)[16])smem;
    const int r0 = (bid & 7) * 1024 + tid;
    const int c0 = (bid >> 3) * CB_CODES;
    {
      int ci = tid >> 1, half = tid & 1;
      const float4* src = reinterpret_cast<const float4*>(cb + (size_t)(c0 + ci) * 16 + half * 8);
      float4 v0 = src[0], v1 = src[1];
      float4* dst = reinterpret_cast<float4*>(&csh[ci][half * 8]);
      dst[0] = v0; dst[1] = v1;
    }
    float4 fa[4][4];
    #pragma unroll
    for (int q = 0; q < 4; ++q) {
      const float4* fp = reinterpret_cast<const float4*>(F + (size_t)(r0 + q * 256) * 16);
      fa[q][0] = fp[0]; fa[q][1] = fp[1]; fa[q][2] = fp[2]; fa[q][3] = fp[3];
    }
    __syncthreads();

    float best[4] = {3.4e38f, 3.4e38f, 3.4e38f, 3.4e38f};
    int bidx[4] = {0, 0, 0, 0};
    #pragma unroll 2
    for (int ci = 0; ci < CB_CODES; ++ci) {
      const float4* cvp = reinterpret_cast<const float4*>(&csh[ci][0]);
      float4 c0v = cvp[0], c1v = cvp[1], c2v = cvp[2], c3v = cvp[3];
      #pragma unroll
      for (int q = 0; q < 4; ++q) {
        float dot = fa[q][0].x*c0v.x + fa[q][0].y*c0v.y + fa[q][0].z*c0v.z + fa[q][0].w*c0v.w
                  + fa[q][1].x*c1v.x + fa[q][1].y*c1v.y + fa[q][1].z*c1v.z + fa[q][1].w*c1v.w
                  + fa[q][2].x*c2v.x + fa[q][2].y*c2v.y + fa[q][2].z*c2v.z + fa[q][2].w*c2v.w
                  + fa[q][3].x*c3v.x + fa[q][3].y*c3v.y + fa[q][3].z*c3v.z + fa[q][3].w*c3v.w;
        float d = -dot;
        if (d < best[q]) { best[q] = d; bidx[q] = c0 + ci; }
      }
    }
    #pragma unroll
    for (int q = 0; q < 4; ++q) {
      unsigned int u = __float_as_uint(best[q]);
      unsigned int key = (u & 0x80000000u) ? ~u : (u | 0x80000000u);  // order-preserving
      unsigned long long pk = ((unsigned long long)key << 32) | (unsigned int)bidx[q];
      atomicMin(&amin[r0 + q * 256], pk);
    }
    return;
  }

  // ---- gemm path: 128x128 tile, BK=64, explicit LDS double-buffer ----
  // Per K-step: issue stage(t+1) -> compute(t) -> __syncthreads (drain lands after compute)
  const int gid = bid - TGT_BLOCKS;
  const int wave = tid >> 6;
  const int lane = tid & 63;
  const int xcd = gid & 7, idx = gid >> 3;
  const int bx = xcd * 8 + (idx & 7);
  const int by = idx >> 3;
  const int row0 = by * 128;
  const int col0 = bx * 128;
  const int wr = wave >> 1, wc = wave & 1;
  unsigned char* As = smem;            // [2 bufs][128 rows][64B]
  unsigned char* Bs = smem + 16384;

  f32x4 acc[4][4];
  #pragma unroll
  for (int i = 0; i < 4; ++i)
    #pragma unroll
    for (int j = 0; j < 4; ++j) acc[i][j] = (f32x4){0.f, 0.f, 0.f, 0.f};

  const int lr = lane >> 2;                               // 16 rows per gld16
  const int lcs = (((lane & 3) ^ ((lane >> 3) & 3)) << 4);// pre-swizzled src 16B slot

  const int l15 = lane & 15, l16 = lane >> 4;
  const int sw = (l15 >> 1) & 3;
  const int subo = (l16 & 1) * 8;
  const int lg16 = l16 >> 1;

  // prologue: stage tile 0 into buf 0
  #pragma unroll
  for (int c = 0; c < 2; ++c) {
    int rchunk = (wave * 2 + c) * 16;
    gld16(A + (size_t)(row0 + rchunk + lr) * KDIM + lcs, As + rchunk * 64);
    gld16(B + (size_t)(col0 + rchunk + lr) * KDIM + lcs, Bs + rchunk * 64);
  }
  __syncthreads();

  #pragma unroll
  for (int t = 0; t < 8; ++t) {
    const int cur = (t & 1) * 8192;
    // prefetch next tile into other buffer; stays in flight during compute
    if (t < 7) {
      const int kt = (t + 1) * 64;
      const int nxt = ((t + 1) & 1) * 8192;
      #pragma unroll
      for (int c = 0; c < 2; ++c) {
        int rchunk = (wave * 2 + c) * 16;
        gld16(A + (size_t)(row0 + rchunk + lr) * KDIM + kt + lcs, As + nxt + rchunk * 64);
        gld16(B + (size_t)(col0 + rchunk + lr) * KDIM + kt + lcs, Bs + nxt + rchunk * 64);
      }
    }
    // compute current buffer
    #pragma unroll
    for (int ks = 0; ks < 2; ++ks) {
      const int poff = (((ks * 2 + lg16) ^ sw) << 4) + subo;
      long af[4], bb[4];
      #pragma unroll
      for (int mi = 0; mi < 4; ++mi)
        af[mi] = *(const long*)(As + cur + (wr * 64 + mi * 16 + l15) * 64 + poff);
      #pragma unroll
      for (int ni = 0; ni < 4; ++ni)
        bb[ni] = *(const long*)(Bs + cur + (wc * 64 + ni * 16 + l15) * 64 + poff);
      #pragma unroll
      for (int mi = 0; mi < 4; ++mi)
        #pragma unroll
        for (int ni = 0; ni < 4; ++ni)
          acc[mi][ni] = __builtin_amdgcn_mfma_f32_16x16x32_fp8_fp8(af[mi], bb[ni], acc[mi][ni], 0, 0, 0);
    }
    if (t < 7) __syncthreads();
  }

  // slim epilogue: per-row partial sum(exp(logit))
  float bv[4];
  #pragma unroll
  for (int ni = 0; ni < 4; ++ni)
    bv[ni] = bias[col0 + wc * 64 + ni * 16 + l15];
  #pragma unroll
  for (int mi = 0; mi < 4; ++mi) {
    int rbase = row0 + wr * 64 + mi * 16 + l16 * 4;
    #pragma unroll
    for (int j = 0; j < 4; ++j) {
      float se = 0.f;
      #pragma unroll
      for (int ni = 0; ni < 4; ++ni)
        se += __expf(acc[mi][ni][j] + bv[ni]);
      #pragma unroll
      for (int o = 1; o < 16; o <<= 1) se += __shfl_xor(se, o);
      if (l15 == 0) atomicAdd(&rowsum[rbase + j], se);
    }
  }
}

// ---------------- target logit: tgtlog[r] = A[r].B[tg] + bias[tg] ----------------
__global__ void tgt_logit_kernel(const unsigned char* __restrict__ A,
                                 const unsigned char* __restrict__ B,
                                 const float* __restrict__ bias,
                                 const unsigned long long* __restrict__ amin,
                                 float* __restrict__ tgtlog) {
  const int wv = threadIdx.x >> 6, lane = threadIdx.x & 63;
  const int r = blockIdx.x * 4 + wv;
  const int tg = (int)(amin[r] & 0xffffffffull);
  uint2 ua = reinterpret_cast<const uint2*>(A + (size_t)r * KDIM)[lane];
  uint2 ub = reinterpret_cast<const uint2*>(B + (size_t)tg * KDIM)[lane];
  float s = 0.f;
  const unsigned char* pa = reinterpret_cast<const unsigned char*>(&ua);
  const unsigned char* pb = reinterpret_cast<const unsigned char*>(&ub);
  #pragma unroll
  for (int i = 0; i < 8; ++i) s += fp8d(pa[i]) * fp8d(pb[i]);
  #pragma unroll
  for (int o = 1; o < 64; o <<= 1) s += __shfl_xor(s, o);
  if (lane == 0) tgtlog[r] = s + bias[tg];
}

// ---------------- final masked-mean loss ----------------
__global__ void loss_kernel(const float* __restrict__ rowsum, const float* __restrict__ tgtl,
                            const int* __restrict__ lens, float* __restrict__ out) {
  __shared__ float sh[256];
  __shared__ int shc[256];
  int tid = threadIdx.x;
  float s = 0.f; int c = 0;
  for (int r = tid; r < MROWS; r += 256) {
    int n = r >> 11;
    int t = r & (TSEQ - 1);
    if (t < lens[n]) { s += logf(rowsum[r]) - tgtl[r]; c++; }
  }
  sh[tid] = s; shc[tid] = c;
  __syncthreads();
  for (int o = 128; o > 0; o >>= 1) {
    if (tid < o) { sh[tid] += sh[tid + o]; shc[tid] += shc[tid + o]; }
    __syncthreads();
  }
  if (tid == 0) out[0] = sh[0] / (float)max(shc[0], 1);
}

extern "C" void kernel_launch(void* const* d_in, const int* in_sizes, int n_in,
                              void* d_out, int out_size, void* d_ws, size_t ws_size,
                              hipStream_t stream) {
  const float* feats    = (const float*)d_in[0];
  const float* context  = (const float*)d_in[1];
  const int*   lens     = (const int*)d_in[2];
  const float* proj     = (const float*)d_in[3];
  const float* codebook = (const float*)d_in[4];
  const float* W_enc    = (const float*)d_in[5];
  const float* b_enc    = (const float*)d_in[6];
  float* out = (float*)d_out;

  char* ws = (char*)d_ws;
  unsigned char* A8 = (unsigned char*)(ws);                       // 4 MB
  unsigned char* B8 = (unsigned char*)(ws + 4194304);             // 4 MB
  float* F          = (float*)(ws + 8388608);                     // 512 KB
  unsigned long long* amin = (unsigned long long*)(ws + 8912896); // 64 KB
  float* rowsum     = (float*)(ws + 8978432);                     // 32 KB
  float* tgtlog     = (float*)(ws + 9011200);                     // 32 KB

  // 1) conversions + projection + init
  prep_kernel<<<5664, 256, 0, stream>>>(context, A8, W_enc, B8, feats, proj, F, amin, rowsum);
  // 2) codebook argmax (first 512 blocks)  ||  GEMM(dbuf)+rowsum(exp)
  gemm_targets_kernel<<<TGT_BLOCKS + 4096, 256, 0, stream>>>(A8, B8, b_enc, rowsum, F, codebook, amin);
  // 3) target logit
  tgt_logit_kernel<<<MROWS / 4, 256, 0, stream>>>(A8, B8, b_enc, amin, tgtlog);
  // 4) final loss
  loss_kernel<<<1, 256, 0, stream>>>(rowsum, tgtlog, lens, out);
}